// Round 1
// baseline (560.388 us; speedup 1.0000x reference)
//
#include <hip/hip_runtime.h>

// MsgPassingNN: 3 rounds of edge-MLP + segment_sum + node-MLP.
// N=100000 nodes (D=16), E=3200000 edges.
// fe: 32 -> 9 (relu) -> 9 (relu) -> 9 ; fx: 25 -> 9 (relu) -> 9 (relu) -> 16
//
// R3 structure (changes over R2 marked *):
//   - CSR build once (hist+scan+scatter) -> edges sorted by dst, packed (dst,src) u64.
//   - * BOTH halves of fe layer-1 hoisted per node:
//       base1[n]  = W1_dst^T x_n + b1   (9 floats, stride 12)
//       base_s[n] = W1_src^T x_n        (9 floats, stride 16, 64B-aligned rows
//                                        so the random src-gather hits 1 line)
//     Edge thread now does 9 adds + relu + 81 + 81 FMA (was 144+81+81) and
//     never reads X (64B random gather -> 36B random gather).
//   - * Segmented wave scan driven by ballot/clz distance-to-head instead of
//     re-shuffling d each step (saves 6 bpermutes + 6 compares; numerics
//     identical). Tail lanes atomicAdd to m (~1.3M atomics vs 28.8M naive).
//   - Node kernel applies fx, zeroes m, and precomputes BOTH base1 and base_s
//     for the next round.

constexpr int NN = 100000;
constexpr int NE = 3200000;
constexpr int NB_CNT = (NN + 255) / 256;   // 391

// ---------------- CSR build ----------------

__global__ __launch_bounds__(256) void hist_k(const int* __restrict__ dst,
                                              int* __restrict__ cnt,
                                              unsigned short* __restrict__ rank)
{
    int e = blockIdx.x * 256 + threadIdx.x;
    if (e >= NE) return;
    int d = dst[e];
    rank[e] = (unsigned short)atomicAdd(&cnt[d], 1);
}

__global__ __launch_bounds__(256) void blocksum_k(const int* __restrict__ cnt,
                                                  int* __restrict__ bsum)
{
    __shared__ int red[256];
    int t = threadIdx.x;
    int i = blockIdx.x * 256 + t;
    red[t] = (i < NN) ? cnt[i] : 0;
    __syncthreads();
    for (int off = 128; off > 0; off >>= 1) {
        if (t < off) red[t] += red[t + off];
        __syncthreads();
    }
    if (t == 0) bsum[blockIdx.x] = red[0];
}

__global__ __launch_bounds__(512) void scanpart_k(const int* __restrict__ bsum,
                                                  int* __restrict__ boff, int nb)
{
    __shared__ int s[512];
    int t = threadIdx.x;
    int v = (t < nb) ? bsum[t] : 0;
    s[t] = v;
    __syncthreads();
    for (int off = 1; off < 512; off <<= 1) {
        int a = (t >= off) ? s[t - off] : 0;
        __syncthreads();
        s[t] += a;
        __syncthreads();
    }
    if (t < nb) boff[t] = s[t] - v;   // exclusive
}

__global__ __launch_bounds__(256) void rowstart_k(const int* __restrict__ cnt,
                                                  const int* __restrict__ boff,
                                                  int* __restrict__ row_start)
{
    __shared__ int s[256];
    int t = threadIdx.x;
    int i = blockIdx.x * 256 + t;
    int v = (i < NN) ? cnt[i] : 0;
    s[t] = v;
    __syncthreads();
    for (int off = 1; off < 256; off <<= 1) {
        int a = (t >= off) ? s[t - off] : 0;
        __syncthreads();
        s[t] += a;
        __syncthreads();
    }
    int incl = s[t];
    if (i < NN) row_start[i] = boff[blockIdx.x] + incl - v;
    if (i == NN - 1) row_start[NN] = boff[blockIdx.x] + incl;
}

__global__ __launch_bounds__(256) void scatter_k(const int* __restrict__ src,
                                                 const int* __restrict__ dst,
                                                 const unsigned short* __restrict__ rank,
                                                 const int* __restrict__ row_start,
                                                 unsigned long long* __restrict__ sed)
{
    int e = blockIdx.x * 256 + threadIdx.x;
    if (e >= NE) return;
    int d = dst[e];
    int pos = row_start[d] + (int)rank[e];
    sed[pos] = ((unsigned long long)(unsigned)d << 32) | (unsigned)src[e];
}

// ---------------- round-0 prologue: base1 + base_s from X0, zero m ----------------

__global__ __launch_bounds__(256) void base_k(const float* __restrict__ X,
                                              const float* __restrict__ feW1,
                                              const float* __restrict__ feb1,
                                              float* __restrict__ base1,
                                              float* __restrict__ bases,
                                              float* __restrict__ m)
{
    __shared__ float sW[32 * 12], sb[9];
    const int t = threadIdx.x;
    for (int i = t; i < 288; i += 256) sW[(i / 9) * 12 + (i % 9)] = feW1[i];
    if (t < 9) sb[t] = feb1[t];
    __syncthreads();

    const int n = blockIdx.x * 256 + t;
    if (n >= NN) return;

    float x[16];
    const float4* p = reinterpret_cast<const float4*>(X + (size_t)n * 16);
    #pragma unroll
    for (int q = 0; q < 4; ++q) {
        float4 v = p[q];
        x[4*q] = v.x; x[4*q+1] = v.y; x[4*q+2] = v.z; x[4*q+3] = v.w;
    }
    float bd[9];
    #pragma unroll
    for (int j = 0; j < 9; ++j) bd[j] = sb[j];
    #pragma unroll
    for (int i = 0; i < 16; ++i) {
        const float xi = x[i];
        #pragma unroll
        for (int j = 0; j < 9; ++j) bd[j] = fmaf(xi, sW[i * 12 + j], bd[j]);
    }
    float bs[9];
    #pragma unroll
    for (int j = 0; j < 9; ++j) bs[j] = 0.f;
    #pragma unroll
    for (int i = 0; i < 16; ++i) {
        const float xi = x[i];
        #pragma unroll
        for (int j = 0; j < 9; ++j) bs[j] = fmaf(xi, sW[(16 + i) * 12 + j], bs[j]);
    }
    float* bp = base1 + (size_t)n * 12;
    #pragma unroll
    for (int j = 0; j < 9; ++j) bp[j] = bd[j];
    float* sp = bases + (size_t)n * 16;
    #pragma unroll
    for (int j = 0; j < 9; ++j) sp[j] = bs[j];
    float* mp = m + (size_t)n * 9;
    #pragma unroll
    for (int j = 0; j < 9; ++j) mp[j] = 0.f;
}

// ---------------- edge round: 1 thread / sorted edge ----------------

__global__ __launch_bounds__(256) void edge2_k(
    const float* __restrict__ base1,
    const float* __restrict__ bases,
    const unsigned long long* __restrict__ sed,
    const float* __restrict__ feW2, const float* __restrict__ feb2,
    const float* __restrict__ feW3, const float* __restrict__ feb3,
    float* __restrict__ m)
{
    __shared__ float sW2[9 * 12], sW3[9 * 12], sb2[9], sb3[9];
    const int t = threadIdx.x;
    if (t < 81)  sW2[(t / 9) * 12 + (t % 9)] = feW2[t];
    if (t >= 128 && t < 209) { int i = t - 128; sW3[(i / 9) * 12 + (i % 9)] = feW3[i]; }
    if (t >= 224 && t < 233) sb2[t - 224] = feb2[t - 224];
    if (t >= 240 && t < 249) sb3[t - 240] = feb3[t - 240];
    __syncthreads();

    const int e = blockIdx.x * 256 + t;          // NE % 256 == 0
    const unsigned long long pk = sed[e];
    const int d = (int)(pk >> 32);
    const int s = (int)(pk & 0xffffffffu);

    // h1 = relu(base1[d] + base_s[s]) — both layer-1 halves hoisted per node.
    // base1 runs share d (L1 hits); base_s is the random gather (36B, 1 line).
    float a[9];
    {
        const float4* pb = reinterpret_cast<const float4*>(base1 + (size_t)d * 12);
        float4 b0 = pb[0], b1 = pb[1];
        const float4* ps = reinterpret_cast<const float4*>(bases + (size_t)s * 16);
        float4 c0 = ps[0], c1 = ps[1];
        a[0] = b0.x + c0.x; a[1] = b0.y + c0.y; a[2] = b0.z + c0.z; a[3] = b0.w + c0.w;
        a[4] = b1.x + c1.x; a[5] = b1.y + c1.y; a[6] = b1.z + c1.z; a[7] = b1.w + c1.w;
        a[8] = base1[(size_t)d * 12 + 8] + bases[(size_t)s * 16 + 8];
    }
    #pragma unroll
    for (int j = 0; j < 9; ++j) a[j] = fmaxf(a[j], 0.f);

    float h2[9];
    #pragma unroll
    for (int j = 0; j < 9; ++j) h2[j] = sb2[j];
    #pragma unroll
    for (int i = 0; i < 9; ++i) {
        const float ai = a[i];
        #pragma unroll
        for (int j = 0; j < 9; ++j) h2[j] = fmaf(ai, sW2[i * 12 + j], h2[j]);
    }
    #pragma unroll
    for (int j = 0; j < 9; ++j) h2[j] = fmaxf(h2[j], 0.f);

    float o[9];
    #pragma unroll
    for (int j = 0; j < 9; ++j) o[j] = sb3[j];
    #pragma unroll
    for (int i = 0; i < 9; ++i) {
        const float hi = h2[i];
        #pragma unroll
        for (int j = 0; j < 9; ++j) o[j] = fmaf(hi, sW3[i * 12 + j], o[j]);
    }

    // segmented inclusive scan by d over the 64-lane wave (d sorted).
    // One shuffle + ballot gives each lane its distance to segment head;
    // per-step predicate is then a register compare (numerics identical to
    // the od==d formulation since equal d are contiguous).
    const int lane = t & 63;
    const int dprev = __shfl_up(d, 1);
    const bool head = (lane == 0) || (dprev != d);
    const unsigned long long hm = __ballot(head);
    const int dist = __clzll((long long)(hm << (63 - lane)));  // 0 if head
    #pragma unroll
    for (int off = 1; off < 64; off <<= 1) {
        const bool ok = (dist >= off);
        #pragma unroll
        for (int j = 0; j < 9; ++j) {
            const float ov = __shfl_up(o[j], off);
            o[j] += ok ? ov : 0.f;
        }
    }
    const bool tail = (lane == 63) || (((hm >> (lane + 1)) & 1ull) != 0ull);
    if (tail) {                                  // segment tail
        float* mp = m + (size_t)d * 9;
        #pragma unroll
        for (int j = 0; j < 9; ++j) atomicAdd(mp + j, o[j]);
    }
}

// ---------------- node round: fx MLP + zero m + next base1/base_s ----------------

__global__ __launch_bounds__(256) void node2_k(
    const float* __restrict__ Xin, float* __restrict__ m,
    const float* __restrict__ fxW1, const float* __restrict__ fxb1,
    const float* __restrict__ fxW2, const float* __restrict__ fxb2,
    const float* __restrict__ fxW3, const float* __restrict__ fxb3,
    const float* __restrict__ feW1, const float* __restrict__ feb1,
    float* __restrict__ Xout, float* __restrict__ base1out,
    float* __restrict__ basesout)
{
    __shared__ float sU1[25 * 12], sU2[9 * 12], sU3[9 * 16];
    __shared__ float sW1d[16 * 12], sW1s[16 * 12];
    __shared__ float sNB[34], sEB1[9];
    const int t = threadIdx.x;
    if (t < 225) sU1[(t / 9) * 12 + (t % 9)] = fxW1[t];
    if (t < 81)  sU2[(t / 9) * 12 + (t % 9)] = fxW2[t];
    if (t < 144) sU3[t] = fxW3[t];
    if (t < 144) sW1d[(t / 9) * 12 + (t % 9)] = feW1[t];
    if (t >= 112) { int i = t - 112; sW1s[(i / 9) * 12 + (i % 9)] = feW1[144 + i]; }
    if (t < 9) sNB[t] = fxb1[t];
    if (t >= 32 && t < 41) sNB[9 + (t - 32)] = fxb2[t - 32];
    if (t >= 64 && t < 80) sNB[18 + (t - 64)] = fxb3[t - 64];
    if (t >= 96 && t < 105) sEB1[t - 96] = feb1[t - 96];
    __syncthreads();

    const int n = blockIdx.x * 256 + t;
    if (n >= NN) return;

    float xr[16];
    {
        const float4* p = reinterpret_cast<const float4*>(Xin + (size_t)n * 16);
        #pragma unroll
        for (int q = 0; q < 4; ++q) {
            float4 v = p[q];
            xr[4*q] = v.x; xr[4*q+1] = v.y; xr[4*q+2] = v.z; xr[4*q+3] = v.w;
        }
    }
    float mm[9];
    float* mp = m + (size_t)n * 9;
    #pragma unroll
    for (int j = 0; j < 9; ++j) mm[j] = mp[j];
    #pragma unroll
    for (int j = 0; j < 9; ++j) mp[j] = 0.f;     // ready for next round

    float h1[9];
    #pragma unroll
    for (int j = 0; j < 9; ++j) h1[j] = sNB[j];
    #pragma unroll
    for (int i = 0; i < 16; ++i) {
        const float xi = xr[i];
        #pragma unroll
        for (int j = 0; j < 9; ++j) h1[j] = fmaf(xi, sU1[i * 12 + j], h1[j]);
    }
    #pragma unroll
    for (int i = 0; i < 9; ++i) {
        const float xi = mm[i];
        #pragma unroll
        for (int j = 0; j < 9; ++j) h1[j] = fmaf(xi, sU1[(16 + i) * 12 + j], h1[j]);
    }
    #pragma unroll
    for (int j = 0; j < 9; ++j) h1[j] = fmaxf(h1[j], 0.f);

    float h2[9];
    #pragma unroll
    for (int j = 0; j < 9; ++j) h2[j] = sNB[9 + j];
    #pragma unroll
    for (int i = 0; i < 9; ++i) {
        const float xi = h1[i];
        #pragma unroll
        for (int j = 0; j < 9; ++j) h2[j] = fmaf(xi, sU2[i * 12 + j], h2[j]);
    }
    #pragma unroll
    for (int j = 0; j < 9; ++j) h2[j] = fmaxf(h2[j], 0.f);

    float o[16];
    #pragma unroll
    for (int k = 0; k < 16; ++k) o[k] = sNB[18 + k];
    #pragma unroll
    for (int j = 0; j < 9; ++j) {
        const float hj = h2[j];
        #pragma unroll
        for (int k = 0; k < 16; ++k) o[k] = fmaf(hj, sU3[j * 16 + k], o[k]);
    }

    float4* po = reinterpret_cast<float4*>(Xout + (size_t)n * 16);
    #pragma unroll
    for (int q = 0; q < 4; ++q) {
        float4 v;
        v.x = o[4*q]; v.y = o[4*q+1]; v.z = o[4*q+2]; v.w = o[4*q+3];
        po[q] = v;
    }

    // base1 / base_s for NEXT round's edge kernel
    float b[9];
    #pragma unroll
    for (int j = 0; j < 9; ++j) b[j] = sEB1[j];
    #pragma unroll
    for (int i = 0; i < 16; ++i) {
        const float xi = o[i];
        #pragma unroll
        for (int j = 0; j < 9; ++j) b[j] = fmaf(xi, sW1d[i * 12 + j], b[j]);
    }
    float* bp = base1out + (size_t)n * 12;
    #pragma unroll
    for (int j = 0; j < 9; ++j) bp[j] = b[j];

    float c[9];
    #pragma unroll
    for (int j = 0; j < 9; ++j) c[j] = 0.f;
    #pragma unroll
    for (int i = 0; i < 16; ++i) {
        const float xi = o[i];
        #pragma unroll
        for (int j = 0; j < 9; ++j) c[j] = fmaf(xi, sW1s[i * 12 + j], c[j]);
    }
    float* sp = basesout + (size_t)n * 16;
    #pragma unroll
    for (int j = 0; j < 9; ++j) sp[j] = c[j];
}

extern "C" void kernel_launch(void* const* d_in, const int* in_sizes, int n_in,
                              void* d_out, int out_size, void* d_ws, size_t ws_size,
                              hipStream_t stream)
{
    const float* X0   = (const float*)d_in[0];
    const int*   esrc = (const int*)d_in[1];
    const int*   edst = (const int*)d_in[2];
    const float* feW1 = (const float*)d_in[3];
    const float* feb1 = (const float*)d_in[4];
    const float* feW2 = (const float*)d_in[5];
    const float* feb2 = (const float*)d_in[6];
    const float* feW3 = (const float*)d_in[7];
    const float* feb3 = (const float*)d_in[8];
    const float* fxW1 = (const float*)d_in[9];
    const float* fxb1 = (const float*)d_in[10];
    const float* fxW2 = (const float*)d_in[11];
    const float* fxb2 = (const float*)d_in[12];
    const float* fxW3 = (const float*)d_in[13];
    const float* fxb3 = (const float*)d_in[14];
    float* out = (float*)d_out;

    // workspace layout (4B units). rank overlays {base1,m}: rank is dead after
    // scatter_k; base1/m are first written by base_k which runs after scatter_k.
    float* Xa        = (float*)d_ws;                          // 1,600,000
    int*   cnt       = (int*)(Xa + (size_t)NN * 16);          // 100,000
    int*   row_start = cnt + NN;                              // 100,002 (padded)
    int*   bsum      = row_start + (NN + 2);                  // 392
    int*   boff      = bsum + (NB_CNT + 1);                   // 392
    float* base1     = (float*)(boff + (NB_CNT + 1));         // NN*12 (union start)
    float* mb        = base1 + (size_t)NN * 12;               // NN*9
    float* base_s    = mb + (size_t)NN * 9;                   // NN*16 (64B rows)
    unsigned short* rank = (unsigned short*)base1;            // NE u16 (overlay)
    unsigned long long* sed =
        (unsigned long long*)(base_s + (size_t)NN * 16);      // NE u64

    const dim3 thr(256);
    const dim3 gE(NE / 256);     // 12500
    const dim3 gN(NB_CNT);       // 391

    // ---- CSR build (once per launch) ----
    hipMemsetAsync(cnt, 0, (size_t)NN * sizeof(int), stream);
    hist_k<<<gE, thr, 0, stream>>>(edst, cnt, rank);
    blocksum_k<<<gN, thr, 0, stream>>>(cnt, bsum);
    scanpart_k<<<1, 512, 0, stream>>>(bsum, boff, NB_CNT);
    rowstart_k<<<gN, thr, 0, stream>>>(cnt, boff, row_start);
    scatter_k<<<gE, thr, 0, stream>>>(esrc, edst, rank, row_start, sed);

    // ---- round 0 ----
    base_k<<<gN, thr, 0, stream>>>(X0, feW1, feb1, base1, base_s, mb);
    edge2_k<<<gE, thr, 0, stream>>>(base1, base_s, sed, feW2, feb2, feW3, feb3, mb);
    node2_k<<<gN, thr, 0, stream>>>(X0, mb, fxW1, fxb1, fxW2, fxb2, fxW3, fxb3,
                                    feW1, feb1, Xa, base1, base_s);
    // ---- round 1 ----
    edge2_k<<<gE, thr, 0, stream>>>(base1, base_s, sed, feW2, feb2, feW3, feb3, mb);
    node2_k<<<gN, thr, 0, stream>>>(Xa, mb, fxW1, fxb1, fxW2, fxb2, fxW3, fxb3,
                                    feW1, feb1, out, base1, base_s);
    // ---- round 2 ----
    edge2_k<<<gE, thr, 0, stream>>>(base1, base_s, sed, feW2, feb2, feW3, feb3, mb);
    node2_k<<<gN, thr, 0, stream>>>(out, mb, fxW1, fxb1, fxW2, fxb2, fxW3, fxb3,
                                    feW1, feb1, Xa, base1, base_s);

    // final X lives in Xa (round-2 node output) -> copy to out
    hipMemcpyAsync(out, Xa, (size_t)NN * 16 * sizeof(float),
                   hipMemcpyDeviceToDevice, stream);
}